// Round 12
// baseline (878.463 us; speedup 1.0000x reference)
//
#include <hip/hip_runtime.h>

#define NN 100000
#define NE 1600000
#define NP 200000
#define CH 128
#define LK 264    // padded LDS row stride (fp16 elems)

#define BSH 6                    // 64 nodes per bucket
#define NB  1563                 // ceil(NN / 64)
#define G1  256                  // hist/scatter grid
#define EPB (NE / G1)            // 6250 edges per block
#define CAP3 4096                // finalize LDS edge capacity (mean bucket = 1024)
#define NCAST 6250               // cast blocks: NN*CH/8 / 256

typedef _Float16 f16x8 __attribute__((ext_vector_type(8)));
typedef _Float16 f16x4 __attribute__((ext_vector_type(4)));
typedef float f32x4 __attribute__((ext_vector_type(4)));

// ---- fused prep: [0,NCAST) cast x->fp16 | [NCAST,NCAST+G1) bucket hist | rest: weight prep ----
__global__ __launch_bounds__(256)
void fused_prep_kernel(const float* __restrict__ x, _Float16* __restrict__ xh,
                       const int* __restrict__ dst, int* __restrict__ hist,
                       const float* __restrict__ w1r, const float* __restrict__ w1o,
                       const float* __restrict__ w2r, const float* __restrict__ w2o,
                       _Float16* __restrict__ w1t, _Float16* __restrict__ w2t) {
    __shared__ int s_h[NB];
    const int bb = blockIdx.x, tid = threadIdx.x;
    if (bb < NCAST) {
        int i = bb * 256 + tid;   // i < 1.6M exactly
        const float4* p = (const float4*)x + (size_t)i * 2;
        float4 a = p[0], b = p[1];
        f16x8 o = { (_Float16)a.x, (_Float16)a.y, (_Float16)a.z, (_Float16)a.w,
                    (_Float16)b.x, (_Float16)b.y, (_Float16)b.z, (_Float16)b.w };
        *((f16x8*)xh + i) = o;
    } else if (bb < NCAST + G1) {
        int g = bb - NCAST;
        for (int i = tid; i < NB; i += 256) s_h[i] = 0;
        __syncthreads();
        int start = g * EPB, end = start + EPB;
        for (int e = start + tid; e < end; e += 256)
            atomicAdd(&s_h[dst[e] >> BSH], 1);
        __syncthreads();
        int* row = hist + (size_t)g * NB;
        for (int i = tid; i < NB; i += 256) row[i] = s_h[i];
    } else {
        int idx = (bb - NCAST - G1) * 256 + tid;   // < 65536
        int which = idx >> 15;
        int li = idx & 32767;
        int n = li >> 8, k = li & 255;
        const float* wr = which ? w2r : w1r;
        const float* wo = which ? w2o : w1o;
        _Float16* wt = which ? w2t : w1t;
        float v = (k < 128) ? wr[k * 128 + n] : wo[(k - 128) * 128 + n];
        wt[li] = (_Float16)v;
    }
}

// ---- column exclusive scan over g — one wave per bucket ----
__global__ __launch_bounds__(256)
void colscan_kernel(int* __restrict__ hist, int* __restrict__ totals) {
    int b = blockIdx.x * 4 + (threadIdx.x >> 6);
    if (b >= NB) return;
    int lane = threadIdx.x & 63;
    size_t base = (size_t)(lane * 4) * NB + b;
    int v0 = hist[base];
    int v1 = hist[base + NB];
    int v2 = hist[base + 2 * (size_t)NB];
    int v3 = hist[base + 3 * (size_t)NB];
    int s0 = v0, s1 = s0 + v1, s2 = s1 + v2, s3 = s2 + v3;
    int incl = s3;
#pragma unroll
    for (int off = 1; off < 64; off <<= 1) {
        int n = __shfl_up(incl, off, 64);
        if (lane >= off) incl += n;
    }
    int excl = incl - s3;
    hist[base] = excl;
    hist[base + NB] = excl + s0;
    hist[base + 2 * (size_t)NB] = excl + s1;
    hist[base + 3 * (size_t)NB] = excl + s2;
    if (lane == 63) totals[b] = incl;
}

// ---- exclusive scan of bucket totals -> base[NB+1] ----
__global__ __launch_bounds__(1024)
void scanB_kernel(const int* __restrict__ totals, int* __restrict__ base) {
    __shared__ int s[2048];
    int tid = threadIdx.x;
    for (int i = tid; i < 2048; i += 1024) s[i] = (i < NB) ? totals[i] : 0;
    __syncthreads();
    for (int off = 1; off < 2048; off <<= 1) {
        int i0 = tid, i1 = tid + 1024;
        int v0 = (i0 >= off) ? s[i0 - off] : 0;
        int v1 = (i1 >= off) ? s[i1 - off] : 0;
        __syncthreads();
        s[i0] += v0; s[i1] += v1;
        __syncthreads();
    }
    if (tid == 0) base[0] = 0;
    for (int i = tid; i < NB; i += 1024) base[i + 1] = s[i];
}

// ---- scatter edges into bucket regions; x = src | dst_local<<17, y = fp32 weight ----
__global__ __launch_bounds__(512)
void bucket_scatter_kernel(const int* __restrict__ src, const int* __restrict__ dst,
                           const float* __restrict__ ew, const int* __restrict__ hist,
                           const int* __restrict__ base, int2* __restrict__ tmp) {
    __shared__ int s_cur[NB];
    const int* row = hist + (size_t)blockIdx.x * NB;
    for (int i = threadIdx.x; i < NB; i += 512) s_cur[i] = base[i] + row[i];
    __syncthreads();
    int start = blockIdx.x * EPB, end = start + EPB;
    for (int e = start + threadIdx.x; e < end; e += 512) {
        int d = dst[e];
        int b = d >> BSH;
        int pos = atomicAdd(&s_cur[b], 1);
        tmp[pos] = make_int2(src[e] | ((d & 63) << 17), __float_as_int(ew[e]));
    }
}

// ---- finalize: per-bucket node-grouped csr + row_ptr ----
__global__ __launch_bounds__(512)
void bucket_finalize_kernel(const int2* __restrict__ tmp, const int* __restrict__ base,
                            int* __restrict__ row_ptr, int2* __restrict__ csr, int N) {
    __shared__ int2 s_e[CAP3];
    __shared__ int s_cnt[64], s_off[64];
    int b = blockIdx.x;
    int lo = base[b], hi = base[b + 1];
    int size = hi - lo;
    int nbase = b << BSH;
    int ncnt = min(64, N - nbase);
    int tid = threadIdx.x;
    if (tid < 64) s_cnt[tid] = 0;
    bool inlds = (size <= CAP3);
    __syncthreads();
    if (inlds) {
        for (int i = tid; i < size; i += 512) {
            int2 e = tmp[lo + i];
            s_e[i] = e;
            atomicAdd(&s_cnt[(e.x >> 17) & 63], 1);
        }
    } else {
        for (int i = tid; i < size; i += 512) {
            int2 e = tmp[lo + i];
            atomicAdd(&s_cnt[(e.x >> 17) & 63], 1);
        }
    }
    __syncthreads();
    if (tid == 0) {
        int run = 0;
        for (int i = 0; i < 64; i++) { int v = s_cnt[i]; s_off[i] = run; s_cnt[i] = run; run += v; }
    }
    __syncthreads();
    if (tid < ncnt) row_ptr[nbase + tid] = lo + s_off[tid];
    if (b == NB - 1 && tid == 0) row_ptr[N] = hi;
    if (inlds) {
        for (int i = tid; i < size; i += 512) {
            int2 e = s_e[i];
            int dl = (e.x >> 17) & 63;
            int p = atomicAdd(&s_cnt[dl], 1);
            csr[lo + p] = make_int2(e.x & 0x1FFFF, e.y);
        }
    } else {
        for (int i = tid; i < size; i += 512) {
            int2 e = tmp[lo + i];
            int dl = (e.x >> 17) & 63;
            int p = atomicAdd(&s_cnt[dl], 1);
            csr[lo + p] = make_int2(e.x & 0x1FFFF, e.y);
        }
    }
}

// ---- fused gather + MFMA layer: one block (512 thr, 8 waves) per 64-node bucket ----
// Phase 1: dual-stream register gather — each quarter-wave walks TWO adjacent nodes'
//          edge lists concurrently (4 loads in flight/lane), one reduce per pair
// Phase 2: stage self rows; Phase 3: MFMA 64x128 = [agg | self] @ Wt^T + b
template <bool RELU>
__global__ __launch_bounds__(512, 8)
void gatherlayer_kernel(const _Float16* __restrict__ feat, const int* __restrict__ row_ptr,
                        const int2* __restrict__ csr, const _Float16* __restrict__ wt,
                        const float* __restrict__ bias, _Float16* __restrict__ out, int N) {
    __shared__ _Float16 atile[64][LK];   // 33792 B -> 4 blocks/CU = 32 waves/CU

    const int tid = threadIdx.x;
    const int nb = blockIdx.x << BSH;
    const int wave = tid >> 6;          // 0..7
    const int lane = tid & 63;
    const int q = lane >> 4;
    const int l16 = lane & 15;
    const int c8 = l16 << 3;

    // ---- phase 1: 4 node-pairs per wave ----
    for (int pp = 0; pp < 4; pp++) {
        const int localA = wave * 8 + pp * 2;
        const int nodeA = nb + localA;
        if (nodeA >= N) break;                     // pairs align with N%64==32: wave-uniform
        const int r0A = row_ptr[nodeA];
        const int r1A = row_ptr[nodeA + 1];        // == r0B
        const int r1B = row_ptr[nodeA + 2];
        float accA[8] = {0.f,0.f,0.f,0.f,0.f,0.f,0.f,0.f};
        float accB[8] = {0.f,0.f,0.f,0.f,0.f,0.f,0.f,0.f};
        int rA = r0A + q, rB = r1A + q;
        bool hA = rA < r1A, hB = rB < r1B;
        int2 eA, eB; f16x8 vA, vB;
        if (hA) { eA = csr[rA]; vA = *(const f16x8*)&feat[(size_t)eA.x * CH + c8]; }
        if (hB) { eB = csr[rB]; vB = *(const f16x8*)&feat[(size_t)eB.x * CH + c8]; }
        while (__builtin_amdgcn_ballot_w64(hA || hB)) {
            int rA2 = rA + 4, rB2 = rB + 4;
            bool hA2 = hA && (rA2 < r1A);
            bool hB2 = hB && (rB2 < r1B);
            int2 eA2, eB2; f16x8 vA2, vB2;
            if (hA2) { eA2 = csr[rA2]; vA2 = *(const f16x8*)&feat[(size_t)eA2.x * CH + c8]; }
            if (hB2) { eB2 = csr[rB2]; vB2 = *(const f16x8*)&feat[(size_t)eB2.x * CH + c8]; }
            if (hA) {
                float w = __int_as_float(eA.y);
#pragma unroll
                for (int j = 0; j < 8; j++) accA[j] += w * (float)vA[j];
            }
            if (hB) {
                float w = __int_as_float(eB.y);
#pragma unroll
                for (int j = 0; j < 8; j++) accB[j] += w * (float)vB[j];
            }
            rA = rA2; hA = hA2; eA = eA2; vA = vA2;
            rB = rB2; hB = hB2; eB = eB2; vB = vB2;
        }
#pragma unroll
        for (int j = 0; j < 8; j++) {
            accA[j] += __shfl_xor(accA[j], 16, 64);
            accA[j] += __shfl_xor(accA[j], 32, 64);
            accB[j] += __shfl_xor(accB[j], 16, 64);
            accB[j] += __shfl_xor(accB[j], 32, 64);
        }
        if (q == 0) {
            float invA = 1.0f / fmaxf((float)(r1A - r0A), 1.0f);
            float invB = 1.0f / fmaxf((float)(r1B - r1A), 1.0f);
            f16x8 oA, oB;
#pragma unroll
            for (int j = 0; j < 8; j++) {
                oA[j] = (_Float16)(accA[j] * invA);
                oB[j] = (_Float16)(accB[j] * invB);
            }
            *(f16x8*)&atile[localA][c8] = oA;
            *(f16x8*)&atile[localA + 1][c8] = oB;
        }
    }

    // ---- phase 2: stage self rows (coalesced) ----
    for (int i = tid; i < 64 * 16; i += 512) {
        int rrow = i >> 4;
        int cc8 = (i & 15) << 3;
        int gn = nb + rrow;
        f16x8 v = {};
        if (gn < N) v = *(const f16x8*)&feat[(size_t)gn * CH + cc8];
        *(f16x8*)&atile[rrow][128 + cc8] = v;
    }
    __syncthreads();

    // ---- phase 3: MFMA; wave w -> output cols w*16..w*16+15 ----
    f32x4 ac[4];
#pragma unroll
    for (int m = 0; m < 4; m++) ac[m] = (f32x4){0.f, 0.f, 0.f, 0.f};

    const int ncol = wave * 16 + l16;
    const int kq = q * 8;
#pragma unroll
    for (int ks = 0; ks < 8; ks++) {
        int kbase = ks * 32 + kq;
        f16x8 bf = *(const f16x8*)&wt[(size_t)ncol * 256 + kbase];
#pragma unroll
        for (int m = 0; m < 4; m++) {
            f16x8 af = *(const f16x8*)&atile[m * 16 + l16][kbase];
            ac[m] = __builtin_amdgcn_mfma_f32_16x16x32_f16(af, bf, ac[m], 0, 0, 0);
        }
    }

    float bv = bias[ncol];
#pragma unroll
    for (int m = 0; m < 4; m++) {
#pragma unroll
        for (int r = 0; r < 4; r++) {
            int node = nb + m * 16 + q * 4 + r;
            if (node >= N) continue;
            float v = ac[m][r] + bv;
            if (RELU) v = fmaxf(v, 0.f);
            out[(size_t)node * CH + ncol] = (_Float16)v;
        }
    }
}

// ---- decode: half-wave per pair, f16x4 per lane ----
__global__ void decode_kernel(const _Float16* __restrict__ z,
                              const int* __restrict__ ps,
                              const int* __restrict__ pd,
                              float* __restrict__ out, int P) {
    long tid = (long)blockIdx.x * blockDim.x + threadIdx.x;
    int p = (int)(tid >> 5);
    int lane = (int)(tid & 31);
    if (p >= P) return;
    int s = ps[p], d = pd[p];
    f16x4 a = *(const f16x4*)&z[(size_t)s * CH + lane * 4];
    f16x4 b = *(const f16x4*)&z[(size_t)d * CH + lane * 4];
    float v = (float)a[0] * (float)b[0] + (float)a[1] * (float)b[1]
            + (float)a[2] * (float)b[2] + (float)a[3] * (float)b[3];
#pragma unroll
    for (int off = 16; off > 0; off >>= 1) v += __shfl_xor(v, off, 64);
    if (lane == 0) out[p] = v * 0.08838834764831845f;  // 1/sqrt(128)
}

extern "C" void kernel_launch(void* const* d_in, const int* in_sizes, int n_in,
                              void* d_out, int out_size, void* d_ws, size_t ws_size,
                              hipStream_t stream) {
    const float* x       = (const float*)d_in[0];
    const int*   ei      = (const int*)d_in[1];   // [2, E]: src then dst
    const float* ew      = (const float*)d_in[2];
    const int*   eli     = (const int*)d_in[3];   // [2, P]
    const float* w1_rel  = (const float*)d_in[4];
    const float* b1      = (const float*)d_in[5];
    const float* w1_root = (const float*)d_in[6];
    const float* w2_rel  = (const float*)d_in[7];
    const float* b2      = (const float*)d_in[8];
    const float* w2_root = (const float*)d_in[9];
    float* out = (float*)d_out;

    const int N = NN, E = NE, P = NP;
    const size_t hrow = (size_t)N * CH * sizeof(_Float16);   // 25.6 MB

    char* ws = (char*)d_ws;
    size_t off = 0;
    auto alloc = [&](size_t bytes) { char* p = ws + off; off = (off + bytes + 15) & ~(size_t)15; return p; };
    _Float16* xh  = (_Float16*)alloc(hrow);
    _Float16* hh  = (_Float16*)alloc(hrow);
    _Float16* zh  = (_Float16*)alloc(hrow);
    int* hist     = (int*)alloc((size_t)G1 * NB * 4);    // 1.6 MB
    int* totals   = (int*)alloc((size_t)NB * 4);
    int* base     = (int*)alloc((size_t)(NB + 1) * 4);
    int* row_ptr  = (int*)alloc((size_t)(N + 1) * 4);
    int2* tmp     = (int2*)alloc((size_t)E * 8);         // 12.8 MB
    int2* csr     = (int2*)alloc((size_t)E * 8);         // 12.8 MB
    _Float16* w1t = (_Float16*)alloc((size_t)128 * 256 * 2);
    _Float16* w2t = (_Float16*)alloc((size_t)128 * 256 * 2);

    const int* src = ei;
    const int* dst = ei + E;

    // --- fused prep: cast + hist + weight transpose ---
    fused_prep_kernel<<<NCAST + G1 + 256, 256, 0, stream>>>(
        x, xh, dst, hist, w1_rel, w1_root, w2_rel, w2_root, w1t, w2t);

    // --- CSR build (atomic-free bucketed counting sort) ---
    colscan_kernel<<<(NB + 3) / 4, 256, 0, stream>>>(hist, totals);
    scanB_kernel<<<1, 1024, 0, stream>>>(totals, base);
    bucket_scatter_kernel<<<G1, 512, 0, stream>>>(src, dst, ew, hist, base, tmp);
    bucket_finalize_kernel<<<NB, 512, 0, stream>>>(tmp, base, row_ptr, csr, N);

    // --- fused gather + layer (per 64-node bucket, 512 threads) ---
    gatherlayer_kernel<true><<<NB, 512, 0, stream>>>(xh, row_ptr, csr, w1t, b1, hh, N);
    gatherlayer_kernel<false><<<NB, 512, 0, stream>>>(hh, row_ptr, csr, w2t, b2, zh, N);

    // --- decode ---
    {
        long threads = (long)P * 32;
        decode_kernel<<<(int)((threads + 255) / 256), 256, 0, stream>>>(zh, eli, eli + P, out, P);
    }
}

// Round 13
// 362.759 us; speedup vs baseline: 2.4216x; 2.4216x over previous
//
#include <hip/hip_runtime.h>

#define NN 100000
#define NE 1600000
#define NP 200000
#define CH 128
#define LK 264    // padded LDS row stride (fp16 elems)

#define BSH 6                    // 64 nodes per bucket
#define NB  1563                 // ceil(NN / 64)
#define G1  256                  // hist/scatter grid
#define EPB (NE / G1)            // 6250 edges per block
#define CAP3 4096                // finalize LDS edge capacity (mean bucket = 1024)
#define NCAST 6250               // cast blocks: NN*CH/8 / 256

typedef _Float16 f16x8 __attribute__((ext_vector_type(8)));
typedef _Float16 f16x4 __attribute__((ext_vector_type(4)));
typedef float f32x4 __attribute__((ext_vector_type(4)));

// ---- fused prep: [0,NCAST) cast x->fp16 | [NCAST,NCAST+G1) bucket hist | rest: weight prep ----
__global__ __launch_bounds__(256)
void fused_prep_kernel(const float* __restrict__ x, _Float16* __restrict__ xh,
                       const int* __restrict__ dst, int* __restrict__ hist,
                       const float* __restrict__ w1r, const float* __restrict__ w1o,
                       const float* __restrict__ w2r, const float* __restrict__ w2o,
                       _Float16* __restrict__ w1t, _Float16* __restrict__ w2t) {
    __shared__ int s_h[NB];
    const int bb = blockIdx.x, tid = threadIdx.x;
    if (bb < NCAST) {
        int i = bb * 256 + tid;   // i < 1.6M exactly
        const float4* p = (const float4*)x + (size_t)i * 2;
        float4 a = p[0], b = p[1];
        f16x8 o = { (_Float16)a.x, (_Float16)a.y, (_Float16)a.z, (_Float16)a.w,
                    (_Float16)b.x, (_Float16)b.y, (_Float16)b.z, (_Float16)b.w };
        *((f16x8*)xh + i) = o;
    } else if (bb < NCAST + G1) {
        int g = bb - NCAST;
        for (int i = tid; i < NB; i += 256) s_h[i] = 0;
        __syncthreads();
        int start = g * EPB, end = start + EPB;
        for (int e = start + tid; e < end; e += 256)
            atomicAdd(&s_h[dst[e] >> BSH], 1);
        __syncthreads();
        int* row = hist + (size_t)g * NB;
        for (int i = tid; i < NB; i += 256) row[i] = s_h[i];
    } else {
        int idx = (bb - NCAST - G1) * 256 + tid;   // < 65536
        int which = idx >> 15;
        int li = idx & 32767;
        int n = li >> 8, k = li & 255;
        const float* wr = which ? w2r : w1r;
        const float* wo = which ? w2o : w1o;
        _Float16* wt = which ? w2t : w1t;
        float v = (k < 128) ? wr[k * 128 + n] : wo[(k - 128) * 128 + n];
        wt[li] = (_Float16)v;
    }
}

// ---- column exclusive scan over g — one wave per bucket ----
__global__ __launch_bounds__(256)
void colscan_kernel(int* __restrict__ hist, int* __restrict__ totals) {
    int b = blockIdx.x * 4 + (threadIdx.x >> 6);
    if (b >= NB) return;
    int lane = threadIdx.x & 63;
    size_t base = (size_t)(lane * 4) * NB + b;
    int v0 = hist[base];
    int v1 = hist[base + NB];
    int v2 = hist[base + 2 * (size_t)NB];
    int v3 = hist[base + 3 * (size_t)NB];
    int s0 = v0, s1 = s0 + v1, s2 = s1 + v2, s3 = s2 + v3;
    int incl = s3;
#pragma unroll
    for (int off = 1; off < 64; off <<= 1) {
        int n = __shfl_up(incl, off, 64);
        if (lane >= off) incl += n;
    }
    int excl = incl - s3;
    hist[base] = excl;
    hist[base + NB] = excl + s0;
    hist[base + 2 * (size_t)NB] = excl + s1;
    hist[base + 3 * (size_t)NB] = excl + s2;
    if (lane == 63) totals[b] = incl;
}

// ---- exclusive scan of bucket totals -> base[NB+1] ----
__global__ __launch_bounds__(1024)
void scanB_kernel(const int* __restrict__ totals, int* __restrict__ base) {
    __shared__ int s[2048];
    int tid = threadIdx.x;
    for (int i = tid; i < 2048; i += 1024) s[i] = (i < NB) ? totals[i] : 0;
    __syncthreads();
    for (int off = 1; off < 2048; off <<= 1) {
        int i0 = tid, i1 = tid + 1024;
        int v0 = (i0 >= off) ? s[i0 - off] : 0;
        int v1 = (i1 >= off) ? s[i1 - off] : 0;
        __syncthreads();
        s[i0] += v0; s[i1] += v1;
        __syncthreads();
    }
    if (tid == 0) base[0] = 0;
    for (int i = tid; i < NB; i += 1024) base[i + 1] = s[i];
}

// ---- scatter edges into bucket regions; x = src | dst_local<<17, y = fp32 weight ----
__global__ __launch_bounds__(512)
void bucket_scatter_kernel(const int* __restrict__ src, const int* __restrict__ dst,
                           const float* __restrict__ ew, const int* __restrict__ hist,
                           const int* __restrict__ base, int2* __restrict__ tmp) {
    __shared__ int s_cur[NB];
    const int* row = hist + (size_t)blockIdx.x * NB;
    for (int i = threadIdx.x; i < NB; i += 512) s_cur[i] = base[i] + row[i];
    __syncthreads();
    int start = blockIdx.x * EPB, end = start + EPB;
    for (int e = start + threadIdx.x; e < end; e += 512) {
        int d = dst[e];
        int b = d >> BSH;
        int pos = atomicAdd(&s_cur[b], 1);
        tmp[pos] = make_int2(src[e] | ((d & 63) << 17), __float_as_int(ew[e]));
    }
}

// ---- finalize: per-bucket node-grouped csr + row_ptr ----
__global__ __launch_bounds__(512)
void bucket_finalize_kernel(const int2* __restrict__ tmp, const int* __restrict__ base,
                            int* __restrict__ row_ptr, int2* __restrict__ csr, int N) {
    __shared__ int2 s_e[CAP3];
    __shared__ int s_cnt[64], s_off[64];
    int b = blockIdx.x;
    int lo = base[b], hi = base[b + 1];
    int size = hi - lo;
    int nbase = b << BSH;
    int ncnt = min(64, N - nbase);
    int tid = threadIdx.x;
    if (tid < 64) s_cnt[tid] = 0;
    bool inlds = (size <= CAP3);
    __syncthreads();
    if (inlds) {
        for (int i = tid; i < size; i += 512) {
            int2 e = tmp[lo + i];
            s_e[i] = e;
            atomicAdd(&s_cnt[(e.x >> 17) & 63], 1);
        }
    } else {
        for (int i = tid; i < size; i += 512) {
            int2 e = tmp[lo + i];
            atomicAdd(&s_cnt[(e.x >> 17) & 63], 1);
        }
    }
    __syncthreads();
    if (tid == 0) {
        int run = 0;
        for (int i = 0; i < 64; i++) { int v = s_cnt[i]; s_off[i] = run; s_cnt[i] = run; run += v; }
    }
    __syncthreads();
    if (tid < ncnt) row_ptr[nbase + tid] = lo + s_off[tid];
    if (b == NB - 1 && tid == 0) row_ptr[N] = hi;
    if (inlds) {
        for (int i = tid; i < size; i += 512) {
            int2 e = s_e[i];
            int dl = (e.x >> 17) & 63;
            int p = atomicAdd(&s_cnt[dl], 1);
            csr[lo + p] = make_int2(e.x & 0x1FFFF, e.y);
        }
    } else {
        for (int i = tid; i < size; i += 512) {
            int2 e = tmp[lo + i];
            int dl = (e.x >> 17) & 63;
            int p = atomicAdd(&s_cnt[dl], 1);
            csr[lo + p] = make_int2(e.x & 0x1FFFF, e.y);
        }
    }
}

// ---- fused gather + MFMA layer: one block (512 thr, 8 waves) per 64-node bucket ----
// Phase 1: single-stream register gather, 3-deep software pipeline (3 loads in flight/lane)
// Phase 2: stage self rows; Phase 3: MFMA 64x128 = [agg | self] @ Wt^T + b
template <bool RELU>
__global__ __launch_bounds__(512)
void gatherlayer_kernel(const _Float16* __restrict__ feat, const int* __restrict__ row_ptr,
                        const int2* __restrict__ csr, const _Float16* __restrict__ wt,
                        const float* __restrict__ bias, _Float16* __restrict__ out, int N) {
    __shared__ _Float16 atile[64][LK];   // 33792 B -> 4 blocks/CU = 32 waves/CU

    const int tid = threadIdx.x;
    const int nb = blockIdx.x << BSH;
    const int wave = tid >> 6;          // 0..7
    const int lane = tid & 63;
    const int q = lane >> 4;
    const int l16 = lane & 15;
    const int c8 = l16 << 3;

    // ---- phase 1: gather 8 nodes per wave, 3-deep pipeline, no LDS atomics ----
    for (int nn = 0; nn < 8; nn++) {
        int local_n = wave * 8 + nn;
        int node = nb + local_n;
        if (node >= N) break;                      // wave-uniform
        int r0 = row_ptr[node], r1 = row_ptr[node + 1];
        float acc[8] = {0.f, 0.f, 0.f, 0.f, 0.f, 0.f, 0.f, 0.f};
        int r = r0 + q;
        if (r < r1) {
            int2 e = csr[r];
            f16x8 v = *(const f16x8*)&feat[(size_t)e.x * CH + c8];
            int2 e2; f16x8 v2;
            bool h2 = (r + 4) < r1;
            if (h2) { e2 = csr[r + 4]; v2 = *(const f16x8*)&feat[(size_t)e2.x * CH + c8]; }
            for (int r3 = r + 8; r3 < r1; r3 += 4) {
                int2 e3 = csr[r3];
                f16x8 v3 = *(const f16x8*)&feat[(size_t)e3.x * CH + c8];
                float w = __int_as_float(e.y);
#pragma unroll
                for (int j = 0; j < 8; j++) acc[j] += w * (float)v[j];
                e = e2; v = v2;
                e2 = e3; v2 = v3;
            }
            float w = __int_as_float(e.y);
#pragma unroll
            for (int j = 0; j < 8; j++) acc[j] += w * (float)v[j];
            if (h2) {
                float w2 = __int_as_float(e2.y);
#pragma unroll
                for (int j = 0; j < 8; j++) acc[j] += w2 * (float)v2[j];
            }
        }
#pragma unroll
        for (int j = 0; j < 8; j++) {
            acc[j] += __shfl_xor(acc[j], 16, 64);
            acc[j] += __shfl_xor(acc[j], 32, 64);
        }
        if (q == 0) {
            float inv = 1.0f / fmaxf((float)(r1 - r0), 1.0f);
            f16x8 o;
#pragma unroll
            for (int j = 0; j < 8; j++) o[j] = (_Float16)(acc[j] * inv);
            *(f16x8*)&atile[local_n][c8] = o;
        }
    }

    // ---- phase 2: stage self rows (coalesced) ----
    for (int i = tid; i < 64 * 16; i += 512) {
        int rrow = i >> 4;
        int cc8 = (i & 15) << 3;
        int gn = nb + rrow;
        f16x8 v = {};
        if (gn < N) v = *(const f16x8*)&feat[(size_t)gn * CH + cc8];
        *(f16x8*)&atile[rrow][128 + cc8] = v;
    }
    __syncthreads();

    // ---- phase 3: MFMA; wave w -> output cols w*16..w*16+15 ----
    f32x4 ac[4];
#pragma unroll
    for (int m = 0; m < 4; m++) ac[m] = (f32x4){0.f, 0.f, 0.f, 0.f};

    const int ncol = wave * 16 + l16;
    const int kq = q * 8;
#pragma unroll
    for (int ks = 0; ks < 8; ks++) {
        int kbase = ks * 32 + kq;
        f16x8 bf = *(const f16x8*)&wt[(size_t)ncol * 256 + kbase];
#pragma unroll
        for (int m = 0; m < 4; m++) {
            f16x8 af = *(const f16x8*)&atile[m * 16 + l16][kbase];
            ac[m] = __builtin_amdgcn_mfma_f32_16x16x32_f16(af, bf, ac[m], 0, 0, 0);
        }
    }

    float bv = bias[ncol];
#pragma unroll
    for (int m = 0; m < 4; m++) {
#pragma unroll
        for (int r = 0; r < 4; r++) {
            int node = nb + m * 16 + q * 4 + r;
            if (node >= N) continue;
            float v = ac[m][r] + bv;
            if (RELU) v = fmaxf(v, 0.f);
            out[(size_t)node * CH + ncol] = (_Float16)v;
        }
    }
}

// ---- decode: half-wave per pair, f16x4 per lane ----
__global__ void decode_kernel(const _Float16* __restrict__ z,
                              const int* __restrict__ ps,
                              const int* __restrict__ pd,
                              float* __restrict__ out, int P) {
    long tid = (long)blockIdx.x * blockDim.x + threadIdx.x;
    int p = (int)(tid >> 5);
    int lane = (int)(tid & 31);
    if (p >= P) return;
    int s = ps[p], d = pd[p];
    f16x4 a = *(const f16x4*)&z[(size_t)s * CH + lane * 4];
    f16x4 b = *(const f16x4*)&z[(size_t)d * CH + lane * 4];
    float v = (float)a[0] * (float)b[0] + (float)a[1] * (float)b[1]
            + (float)a[2] * (float)b[2] + (float)a[3] * (float)b[3];
#pragma unroll
    for (int off = 16; off > 0; off >>= 1) v += __shfl_xor(v, off, 64);
    if (lane == 0) out[p] = v * 0.08838834764831845f;  // 1/sqrt(128)
}

extern "C" void kernel_launch(void* const* d_in, const int* in_sizes, int n_in,
                              void* d_out, int out_size, void* d_ws, size_t ws_size,
                              hipStream_t stream) {
    const float* x       = (const float*)d_in[0];
    const int*   ei      = (const int*)d_in[1];   // [2, E]: src then dst
    const float* ew      = (const float*)d_in[2];
    const int*   eli     = (const int*)d_in[3];   // [2, P]
    const float* w1_rel  = (const float*)d_in[4];
    const float* b1      = (const float*)d_in[5];
    const float* w1_root = (const float*)d_in[6];
    const float* w2_rel  = (const float*)d_in[7];
    const float* b2      = (const float*)d_in[8];
    const float* w2_root = (const float*)d_in[9];
    float* out = (float*)d_out;

    const int N = NN, E = NE, P = NP;
    const size_t hrow = (size_t)N * CH * sizeof(_Float16);   // 25.6 MB

    char* ws = (char*)d_ws;
    size_t off = 0;
    auto alloc = [&](size_t bytes) { char* p = ws + off; off = (off + bytes + 15) & ~(size_t)15; return p; };
    _Float16* xh  = (_Float16*)alloc(hrow);
    _Float16* hh  = (_Float16*)alloc(hrow);
    _Float16* zh  = (_Float16*)alloc(hrow);
    int* hist     = (int*)alloc((size_t)G1 * NB * 4);    // 1.6 MB
    int* totals   = (int*)alloc((size_t)NB * 4);
    int* base     = (int*)alloc((size_t)(NB + 1) * 4);
    int* row_ptr  = (int*)alloc((size_t)(N + 1) * 4);
    int2* tmp     = (int2*)alloc((size_t)E * 8);         // 12.8 MB
    int2* csr     = (int2*)alloc((size_t)E * 8);         // 12.8 MB
    _Float16* w1t = (_Float16*)alloc((size_t)128 * 256 * 2);
    _Float16* w2t = (_Float16*)alloc((size_t)128 * 256 * 2);

    const int* src = ei;
    const int* dst = ei + E;

    // --- fused prep: cast + hist + weight transpose ---
    fused_prep_kernel<<<NCAST + G1 + 256, 256, 0, stream>>>(
        x, xh, dst, hist, w1_rel, w1_root, w2_rel, w2_root, w1t, w2t);

    // --- CSR build (atomic-free bucketed counting sort) ---
    colscan_kernel<<<(NB + 3) / 4, 256, 0, stream>>>(hist, totals);
    scanB_kernel<<<1, 1024, 0, stream>>>(totals, base);
    bucket_scatter_kernel<<<G1, 512, 0, stream>>>(src, dst, ew, hist, base, tmp);
    bucket_finalize_kernel<<<NB, 512, 0, stream>>>(tmp, base, row_ptr, csr, N);

    // --- fused gather + layer (per 64-node bucket, 512 threads) ---
    gatherlayer_kernel<true><<<NB, 512, 0, stream>>>(xh, row_ptr, csr, w1t, b1, hh, N);
    gatherlayer_kernel<false><<<NB, 512, 0, stream>>>(hh, row_ptr, csr, w2t, b2, zh, N);

    // --- decode ---
    {
        long threads = (long)P * 32;
        decode_kernel<<<(int)((threads + 255) / 256), 256, 0, stream>>>(zh, eli, eli + P, out, P);
    }
}